// Round 13
// baseline (539.725 us; speedup 1.0000x reference)
//
#include <hip/hip_runtime.h>
#include <hip/hip_bf16.h>

#define N_TOK 8192
#define DIM   1024
#define HID   4096
#define NEXP  8
#define CSTR  64    // counts stride in ints
#define RTMAX 72    // worst-case total 256-row tiles (16384/256 + 8 partials)
#define HROWS 16896 // hbuf/ybuf row capacity
#define EPS   264   // epilogue LDS stride (shorts)
#define NG1   1152  // gemm1 gemm-blocks (8*2*RTMAX); w2-transpose blocks appended

using bf16x8 = __attribute__((ext_vector_type(8))) short;
using f32x4  = __attribute__((ext_vector_type(4))) float;

__device__ __forceinline__ void gload_lds16(const void* g, void* l) {
  __builtin_amdgcn_global_load_lds(
      (const __attribute__((address_space(1))) unsigned int*)g,
      (__attribute__((address_space(3))) unsigned int*)l, 16, 0, 0);
}

__device__ __forceinline__ float wredsum(float v) {
#pragma unroll
  for (int off = 32; off > 0; off >>= 1) v += __shfl_xor(v, off, 64);
  return v;
}

__device__ __forceinline__ unsigned short f2bf(float f) {
  __hip_bfloat16 h = __float2bfloat16(f);
  return *reinterpret_cast<unsigned short*>(&h);
}
__device__ __forceinline__ float bf2f(unsigned short u) {
  return __uint_as_float((unsigned)u << 16);
}

// ---------------- transpose body: fp32 [R][C] tile -> bf16 [C][R] ----------------
__device__ __forceinline__ void transpose_body(
    const float* __restrict__ src, __hip_bfloat16* __restrict__ dst,
    int R, int C, int c0, int r0, float (*tile)[65]) {
  const int tid = threadIdx.x;
  const int tx = tid & 15, ty = tid >> 4;
#pragma unroll
  for (int k = 0; k < 4; k++) {
    const int row = ty + k * 16;
    const float4 v = *(const float4*)(src + (size_t)(r0 + row) * C + c0 + tx * 4);
    tile[row][tx * 4 + 0] = v.x; tile[row][tx * 4 + 1] = v.y;
    tile[row][tx * 4 + 2] = v.z; tile[row][tx * 4 + 3] = v.w;
  }
  __syncthreads();
#pragma unroll
  for (int k = 0; k < 4; k++) {
    const int orow = ty + k * 16;
    ushort4 st;
    st.x = f2bf(tile[tx * 4 + 0][orow]);
    st.y = f2bf(tile[tx * 4 + 1][orow]);
    st.z = f2bf(tile[tx * 4 + 2][orow]);
    st.w = f2bf(tile[tx * 4 + 3][orow]);
    *(ushort4*)((unsigned short*)dst + (size_t)(c0 + orow) * R + r0 + tx * 4) = st;
  }
}

// ---------------- setup: fused {w1 transpose | prep}  (w2 transpose rides gemm1) ----------------
__global__ __launch_bounds__(256) void setup_kernel(
    const float* __restrict__ x, const float* __restrict__ gamma, const float* __restrict__ beta,
    const float* __restrict__ conf_w, const float* __restrict__ conf_b,
    const float* __restrict__ rw, const float* __restrict__ rb,
    const float* __restrict__ w1,
    __hip_bfloat16* __restrict__ w1t,
    __hip_bfloat16* __restrict__ xn, float* __restrict__ out,
    int* __restrict__ counts, int* __restrict__ lists, float* __restrict__ wts,
    int2* __restrict__ idx) {
  __shared__ float tile[64][65];
  const int b = (int)blockIdx.x;
  if (b < 8192) {
    const int z = b >> 10, r = b & 1023;
    const int cx = r & 63, ry = r >> 6;
    transpose_body(w1 + (size_t)z * DIM * HID, w1t + (size_t)z * DIM * HID,
                   DIM, HID, cx * 64, ry * 64, tile);
    return;
  }
  // ---- prep ----
  const int t = (b - 8192) * 4 + ((int)threadIdx.x >> 6);
  const int lane = threadIdx.x & 63;
  const float* xr = x + (size_t)t * DIM;

  float4 xv[4];
#pragma unroll
  for (int q = 0; q < 4; q++) xv[q] = *(const float4*)(xr + q * 256 + lane * 4);

  float s = 0.f, s2 = 0.f;
#pragma unroll
  for (int q = 0; q < 4; q++) {
    s  += xv[q].x + xv[q].y + xv[q].z + xv[q].w;
    s2 += xv[q].x * xv[q].x + xv[q].y * xv[q].y + xv[q].z * xv[q].z + xv[q].w * xv[q].w;
  }
  s = wredsum(s); s2 = wredsum(s2);
  const float mu  = s * (1.f / DIM);
  const float inv = rsqrtf(s2 * (1.f / DIM) - mu * mu + 1e-5f);

  float p[9];
#pragma unroll
  for (int e = 0; e < 9; e++) p[e] = 0.f;

#pragma unroll
  for (int q = 0; q < 4; q++) {
    const int d0 = q * 256 + lane * 4;
    const float4 g4 = *(const float4*)(gamma + d0);
    const float4 b4 = *(const float4*)(beta + d0);
    float v0 = (xv[q].x - mu) * inv * g4.x + b4.x;
    float v1 = (xv[q].y - mu) * inv * g4.y + b4.y;
    float v2 = (xv[q].z - mu) * inv * g4.z + b4.z;
    float v3 = (xv[q].w - mu) * inv * g4.w + b4.w;

    ushort4 st; st.x = f2bf(v0); st.y = f2bf(v1); st.z = f2bf(v2); st.w = f2bf(v3);
    *(ushort4*)((unsigned short*)xn + (size_t)t * DIM + d0) = st;
    *(float4*)(out + (size_t)N_TOK * DIM + N_TOK + (size_t)t * DIM + d0) = xv[q];

    const float vv[4] = {v0, v1, v2, v3};
#pragma unroll
    for (int j = 0; j < 4; j++) {
      const int d = d0 + j;
      const float v = vv[j];
      p[8] += v * conf_w[d];
      const float4 r0 = *(const float4*)(rw + d * 8);
      const float4 r1 = *(const float4*)(rw + d * 8 + 4);
      p[0] += v * r0.x; p[1] += v * r0.y; p[2] += v * r0.z; p[3] += v * r0.w;
      p[4] += v * r1.x; p[5] += v * r1.y; p[6] += v * r1.z; p[7] += v * r1.w;
    }
  }
#pragma unroll
  for (int e = 0; e < 9; e++) p[e] = wredsum(p[e]);

  if (lane == 0) {
    float L[8];
#pragma unroll
    for (int e = 0; e < 8; e++) L[e] = p[e] + rb[e];
    const float cl = p[8] + conf_b[0];
    out[(size_t)N_TOK * DIM + t] = 1.f / (1.f + expf(-cl));

    float mx = L[0];
#pragma unroll
    for (int e = 1; e < 8; e++) mx = fmaxf(mx, L[e]);
    float pe[8];
#pragma unroll
    for (int e = 0; e < 8; e++) pe[e] = expf(L[e] - mx);
    int i0 = 0; float v0 = pe[0];
#pragma unroll
    for (int e = 1; e < 8; e++) if (pe[e] > v0) { v0 = pe[e]; i0 = e; }
    int i1 = -1; float v1 = -1.f;
#pragma unroll
    for (int e = 0; e < 8; e++) if (e != i0 && pe[e] > v1) { v1 = pe[e]; i1 = e; }
    const float wsum = v0 + v1;
    const float w0 = v0 / wsum, w1v = v1 / wsum;
    int p0 = atomicAdd(&counts[i0 * CSTR], 1);
    lists[i0 * N_TOK + p0] = t; wts[i0 * N_TOK + p0] = w0;
    int p1 = atomicAdd(&counts[i1 * CSTR], 1);
    lists[i1 * N_TOK + p1] = t; wts[i1 * N_TOK + p1] = w1v;
    idx[t] = make_int2((i0 << 13) | p0, (i1 << 13) | p1);
  }
}

// ---------------- prefix sums: bases (rows) and meta (256-row tiles) ----------------
__global__ void bases_kernel(const int* __restrict__ counts, int* __restrict__ bases,
                             int* __restrict__ meta) {
  if (threadIdx.x == 0) {
    int s = 0, r = 0;
#pragma unroll
    for (int e = 0; e < NEXP; e++) {
      bases[e] = s; meta[e] = r;
      const int c = counts[e * CSTR];
      s += c; r += (c + 255) >> 8;
    }
    meta[NEXP] = r;
  }
}

// ===== 256x256 / BK=32 / 4 waves (per-wave 128x128, acc[8][8]) / 2-slot depth-1 =====
// Slot s (32 KB) at s*32768: A [256 rows][32] bf16 at +0, B [256 rows][32] at +16384.
// Row = 64 B = 4 x 16B chunks; elem (r,k) at r*64 + ((k>>3) ^ ((r>>1)&3))*16 + (k&7)*2.
// gload_lds dest linear; swizzle pre-applied to SOURCE and identically on ds_read
// (rule 21). 4 waves (2 wr x 2 wc); wave = rows wr*128..+128 x cols wc*128..+128:
// 16 ds_read_b128 -> 64 MFMA = 0.25 reads/MFMA (r11 was 0.375) -> per block-tile
// LDS 64 KB (~750 cyc) vs MFMA 8.4 MFLOP (~2480 cyc-CU): MFMA-bound, 1.9x margin.
// Per tile t: vmcnt(0) [stage(t) landed; issued a full tile ago -> no stall];
// s_barrier [all waves past tile t-1 reads -> slot t^1 free]; stage(t+1) into
// slot t^1 (WAR-safe); reads {a0,a1,b0..b7,a2..a7}; 2D MFMA groups gated by
// counted lgkm: (m01,n01)@12 (m01,n23)@10 (m01,n45)@8 (m01,n67)@6
// (m23,*)@4 (m45,*)@2 (m67,*)@0.

#define LGKM_SB(N)                                                            \
  asm volatile("s_waitcnt lgkmcnt(" #N ")" ::: "memory");                     \
  __builtin_amdgcn_sched_barrier(0);

#define MFMA_BLK(M0, NM, N0, NN)                                              \
  __builtin_amdgcn_s_setprio(1);                                              \
  _Pragma("unroll")                                                           \
  for (int m = (M0); m < (M0) + (NM); m++)                                    \
    _Pragma("unroll")                                                         \
    for (int n = (N0); n < (N0) + (NN); n++)                                  \
      acc[m][n] = __builtin_amdgcn_mfma_f32_16x16x32_bf16(afr[m], bfr[n], acc[m][n], 0, 0, 0); \
  __builtin_amdgcn_s_setprio(0);

#define GEMM_CORE(NT)                                                                   \
  f32x4 acc[8][8] = {};                                                                 \
  stage(0, 0);                                                                          \
  for (int t = 0; t < (NT); ++t) {                                                      \
    const int pb = (t & 1) * 32768;                                                     \
    asm volatile("s_waitcnt vmcnt(0)" ::: "memory");                                    \
    __builtin_amdgcn_s_barrier();                                                       \
    if (t + 1 < (NT)) stage(t + 1, (~t & 1) * 32768);                                   \
    const char* Ab = smem + pb + Abase;                                                 \
    const char* Bb = smem + pb + Bbase;                                                 \
    bf16x8 bfr[8], afr[8];                                                              \
    afr[0] = *(const bf16x8*)(Ab);                                                      \
    afr[1] = *(const bf16x8*)(Ab + 1024);                                               \
    bfr[0] = *(const bf16x8*)(Bb);                                                      \
    bfr[1] = *(const bf16x8*)(Bb + 1024);                                               \
    __builtin_amdgcn_sched_barrier(0);                                                  \
    bfr[2] = *(const bf16x8*)(Bb + 2048);                                               \
    bfr[3] = *(const bf16x8*)(Bb + 3072);                                               \
    __builtin_amdgcn_sched_barrier(0);                                                  \
    bfr[4] = *(const bf16x8*)(Bb + 4096);                                               \
    bfr[5] = *(const bf16x8*)(Bb + 5120);                                               \
    __builtin_amdgcn_sched_barrier(0);                                                  \
    bfr[6] = *(const bf16x8*)(Bb + 6144);                                               \
    bfr[7] = *(const bf16x8*)(Bb + 7168);                                               \
    __builtin_amdgcn_sched_barrier(0);                                                  \
    afr[2] = *(const bf16x8*)(Ab + 2048);                                               \
    afr[3] = *(const bf16x8*)(Ab + 3072);                                               \
    __builtin_amdgcn_sched_barrier(0);                                                  \
    afr[4] = *(const bf16x8*)(Ab + 4096);                                               \
    afr[5] = *(const bf16x8*)(Ab + 5120);                                               \
    __builtin_amdgcn_sched_barrier(0);                                                  \
    afr[6] = *(const bf16x8*)(Ab + 6144);                                               \
    afr[7] = *(const bf16x8*)(Ab + 7168);                                               \
    __builtin_amdgcn_sched_barrier(0);                                                  \
    LGKM_SB(12) MFMA_BLK(0, 2, 0, 2)                                                    \
    LGKM_SB(10) MFMA_BLK(0, 2, 2, 2)                                                    \
    LGKM_SB(8)  MFMA_BLK(0, 2, 4, 2)                                                    \
    LGKM_SB(6)  MFMA_BLK(0, 2, 6, 2)                                                    \
    LGKM_SB(4)  MFMA_BLK(2, 2, 0, 8)                                                    \
    LGKM_SB(2)  MFMA_BLK(4, 2, 0, 8)                                                    \
    LGKM_SB(0)  MFMA_BLK(6, 2, 0, 8)                                                    \
  }

#define DECODE_TAIL()                                                         \
  if (rtg >= meta[NEXP]) return;                                              \
  int e = 0;                                                                  \
  _Pragma("unroll")                                                           \
  for (int k = 1; k < NEXP; k++) if (meta[k] <= rtg) e = k;                   \
  const int rt = rtg - meta[e];                                               \
  const int cnt = counts[e * CSTR];                                           \
  const int hbase = bases[e];

#define GEMM_COMMON()                                                         \
  const int tid = threadIdx.x;  /* 256 threads = 4 waves (2x2) */             \
  const int l = tid & 63;                                                     \
  const int w4 = tid >> 6;                                                    \
  const int wr = w4 >> 1;                                                     \
  const int wc = w4 & 1;                                                      \
  const int lr = l & 15;                                                      \
  const int pchunk = (l >> 4) ^ ((lr >> 1) & 3);                              \
  const int Abase = (wr * 128 + lr) * 64 + pchunk * 16;                       \
  const int Bbase = 16384 + (wc * 128 + lr) * 64 + pchunk * 16;               \
  const int srow = tid >> 2;  /* staging row within 64-row unit */            \
  const int lc = (tid & 3) ^ ((srow >> 1) & 3);

// epilogue: 4 passes of 64 rows through LDS bf16 [64][EPS]; 16B/lane stores
#define EPILOGUE(DSTROW)                                                      \
  __builtin_amdgcn_s_barrier();                                               \
  {                                                                           \
    unsigned short* ep = (unsigned short*)smem;                               \
    _Pragma("unroll")                                                         \
    for (int pz = 0; pz < 4; pz++) {                                          \
      if (wr == (pz >> 1)) {                                                  \
        const int mlo = (pz & 1) * 4;                                         \
        _Pragma("unroll")                                                     \
        for (int n = 0; n < 8; n++) {                                         \
          const int col = wc * 128 + n * 16 + lr;                             \
          _Pragma("unroll")                                                   \
          for (int m = 0; m < 4; m++) {                                       \
            f32x4 v = acc[mlo + m][n];                                        \
            _Pragma("unroll")                                                 \
            for (int j = 0; j < 4; j++)                                       \
              ep[(m * 16 + (l >> 4) * 4 + j) * EPS + col] = f2bf(v[j]);       \
          }                                                                   \
        }                                                                     \
      }                                                                       \
      asm volatile("s_waitcnt lgkmcnt(0)" ::: "memory");                      \
      __builtin_amdgcn_s_barrier();                                           \
      const int g = tid >> 5, u = tid & 31;                                   \
      _Pragma("unroll")                                                       \
      for (int i = 0; i < 8; i++) {                                           \
        const int row = i * 8 + g;                                            \
        const int pos = rt * 256 + pz * 64 + row;                             \
        if (pos < cnt) {                                                      \
          bf16x8 vv = *(const bf16x8*)(ep + row * EPS + u * 8);               \
          *(bf16x8*)(DSTROW + u * 8) = vv;                                    \
        }                                                                     \
      }                                                                       \
      __builtin_amdgcn_s_barrier();                                           \
    }                                                                         \
  }

// ---------------- GEMM1 (+ co-scheduled w2 transpose blocks) ----------------
__global__ __launch_bounds__(256, 1) void gemm1_kernel(
    const __hip_bfloat16* __restrict__ xn, const __hip_bfloat16* __restrict__ w1t_b,
    const float* __restrict__ b1, const int* __restrict__ lists,
    const int* __restrict__ counts, const int* __restrict__ bases,
    const int* __restrict__ meta, __hip_bfloat16* __restrict__ hbuf,
    const float* __restrict__ w2, __hip_bfloat16* __restrict__ w2t) {
  __shared__ char smem[65536];
  if ((int)blockIdx.x >= NG1) {
    // w2 transpose: [HID,DIM] fp32 -> [DIM,HID] bf16, 64x64 tiles
    const int bb = (int)blockIdx.x - NG1;
    const int z = bb >> 10, r = bb & 1023;
    const int cx = r & 15, ry = r >> 4;
    transpose_body(w2 + (size_t)z * HID * DIM, w2t + (size_t)z * HID * DIM,
                   HID, DIM, cx * 64, ry * 64, (float(*)[65])smem);
    return;
  }
  const int x_ = (int)blockIdx.x & 7;
  const int q_ = (int)blockIdx.x >> 3;
  const int rtg = q_ >> 1;
  const int panel = x_ * 2 + (q_ & 1);
  DECODE_TAIL()
  const int ct = panel;                      // 16 panels of 256 cols
  const int* list = lists + e * N_TOK;
  const __hip_bfloat16* w1t = w1t_b + (size_t)e * DIM * HID;
  GEMM_COMMON()

  const unsigned short* srcA[4];
  const unsigned short* srcB[4];
#pragma unroll
  for (int j = 0; j < 4; j++) {
    const int pos = rt * 256 + j * 64 + srow;
    const int tok = list[pos < cnt ? pos : 0];
    srcA[j] = (const unsigned short*)xn + (size_t)tok * DIM + lc * 8;
    srcB[j] = (const unsigned short*)w1t + (size_t)(ct * 256 + j * 64 + srow) * DIM + lc * 8;
  }
  auto stage = [&](int tt, int lbase) {
#pragma unroll
    for (int j = 0; j < 4; j++)
      gload_lds16(srcA[j] + tt * 32, smem + lbase + j * 4096 + tid * 16);
#pragma unroll
    for (int j = 0; j < 4; j++)
      gload_lds16(srcB[j] + tt * 32, smem + lbase + 16384 + j * 4096 + tid * 16);
  };

  GEMM_CORE(DIM / 32)

  float bv[8];
#pragma unroll
  for (int n = 0; n < 8; n++) bv[n] = b1[e * HID + ct * 256 + wc * 128 + n * 16 + lr];
#pragma unroll
  for (int n = 0; n < 8; n++)
#pragma unroll
    for (int m = 0; m < 8; m++)
#pragma unroll
      for (int j = 0; j < 4; j++) acc[m][n][j] = fmaxf(acc[m][n][j] + bv[n], 0.f);
  EPILOGUE((unsigned short*)hbuf + (size_t)(hbase + pos) * HID + ct * 256)
}

// ---------------- GEMM2 (split-K x SK): ybuf[ksp][base+pos] = hbuf @ w2t^T ----------------
// SK==2 decode: ksp = xcd&1; 4 ct-panels of one (rt,ksp) co-resident per XCD.
__global__ __launch_bounds__(256, 1) void gemm2_kernel(
    const __hip_bfloat16* __restrict__ hbuf, const __hip_bfloat16* __restrict__ w2t_b,
    const int* __restrict__ counts, const int* __restrict__ bases,
    const int* __restrict__ meta, __hip_bfloat16* __restrict__ ybuf, const int SK) {
  __shared__ char smem[65536];
  int panel, rtg;
  if (SK == 2) {
    const int x_ = (int)blockIdx.x & 7;
    const int q_ = (int)blockIdx.x >> 3;
    rtg = (q_ >> 2) * 4 + (x_ >> 1);
    panel = (x_ & 1) * 4 + (q_ & 3);
  } else {
    panel = (int)blockIdx.x / RTMAX;
    rtg = (int)blockIdx.x - panel * RTMAX;
  }
  DECODE_TAIL()
  const int ct = panel & 3;
  const int ksp = panel >> 2;
  const int kbase = ksp * (HID / SK);
  const __hip_bfloat16* w2t = w2t_b + (size_t)e * DIM * HID;
  GEMM_COMMON()

  const unsigned short* srcA[4];
  const unsigned short* srcB[4];
#pragma unroll
  for (int j = 0; j < 4; j++) {
    srcA[j] = (const unsigned short*)hbuf +
              (size_t)(hbase + rt * 256 + j * 64 + srow) * HID + kbase + lc * 8;
    srcB[j] = (const unsigned short*)w2t +
              (size_t)(ct * 256 + j * 64 + srow) * HID + kbase + lc * 8;
  }
  auto stage = [&](int tt, int lbase) {
#pragma unroll
    for (int j = 0; j < 4; j++)
      gload_lds16(srcA[j] + tt * 32, smem + lbase + j * 4096 + tid * 16);
#pragma unroll
    for (int j = 0; j < 4; j++)
      gload_lds16(srcB[j] + tt * 32, smem + lbase + 16384 + j * 4096 + tid * 16);
  };

  const int nk = (HID / 32) / SK;
  GEMM_CORE(nk)

  EPILOGUE((unsigned short*)ybuf + ((size_t)ksp * HROWS + hbase + pos) * DIM + ct * 256)
}

// ---------------- combine: out[t] = x[t] + sum_a w_a * (sum_s y[s][a] + b2[e_a]) ----------------
__global__ __launch_bounds__(256) void combine_kernel(
    const float* __restrict__ x, const __hip_bfloat16* __restrict__ ybuf,
    const float* __restrict__ b2, const int2* __restrict__ idx,
    const float* __restrict__ wv, const int* __restrict__ bases,
    float* __restrict__ out, const int SK) {
  const int t = blockIdx.x * 4 + (threadIdx.x >> 6);
  const int lane = threadIdx.x & 63;
  const int2 iv = idx[t];
  const int e0 = iv.x >> 13, p0 = iv.x & (N_TOK - 1);
  const int e1 = iv.y >> 13, p1 = iv.y & (N_TOK - 1);
  const float w0 = wv[iv.x], w1 = wv[iv.y];
  const int r0 = bases[e0] + p0;
  const int r1 = bases[e1] + p1;
#pragma unroll
  for (int q = 0; q < 4; q++) {
    const int d0 = q * 256 + lane * 4;
    float4 o = *(const float4*)(x + (size_t)t * DIM + d0);
    float y0x = 0.f, y0y = 0.f, y0z = 0.f, y0w = 0.f;
    float y1x = 0.f, y1y = 0.f, y1z = 0.f, y1w = 0.f;
    for (int s = 0; s < SK; s++) {
      const ushort4 a = *(const ushort4*)((const unsigned short*)ybuf +
                          ((size_t)s * HROWS + r0) * DIM + d0);
      const ushort4 b = *(const ushort4*)((const unsigned short*)ybuf +
                          ((size_t)s * HROWS + r1) * DIM + d0);
      y0x += bf2f(a.x); y0y += bf2f(a.y); y0z += bf2f(a.z); y0w += bf2f(a.w);
      y1x += bf2f(b.x); y1y += bf2f(b.y); y1z += bf2f(b.z); y1w += bf2f(b.w);
    }
    const float4 bb0 = *(const float4*)(b2 + e0 * DIM + d0);
    const float4 bb1 = *(const float4*)(b2 + e1 * DIM + d0);
    o.x += w0 * (y0x + bb0.x) + w1 * (y1x + bb1.x);
    o.y += w0 * (y0y + bb0.y) + w1 * (y1y + bb1.y);
    o.z += w0 * (y0z + bb0.z) + w1 * (y1z + bb1.z);
    o.w += w0 * (y0w + bb0.w) + w1 * (y1w + bb1.w);
    *(float4*)(out + (size_t)t * DIM + d0) = o;
  }
}

extern "C" void kernel_launch(void* const* d_in, const int* in_sizes, int n_in,
                              void* d_out, int out_size, void* d_ws, size_t ws_size,
                              hipStream_t stream) {
  (void)in_sizes; (void)n_in; (void)out_size;
  const float* x      = (const float*)d_in[0];
  const float* gamma  = (const float*)d_in[1];
  const float* beta   = (const float*)d_in[2];
  const float* conf_w = (const float*)d_in[3];
  const float* conf_b = (const float*)d_in[4];
  const float* rw     = (const float*)d_in[5];
  const float* rb     = (const float*)d_in[6];
  const float* w1     = (const float*)d_in[7];
  const float* b1     = (const float*)d_in[8];
  const float* w2     = (const float*)d_in[9];
  const float* b2     = (const float*)d_in[10];
  float* out = (float*)d_out;

  char* w = (char*)d_ws;
  auto alloc = [&](size_t bytes) { char* p = w; w += (bytes + 255) & ~255ULL; return p; };

  __hip_bfloat16* xn = (__hip_bfloat16*)alloc((size_t)N_TOK * DIM * 2);
  int*   lists  = (int*)alloc((size_t)NEXP * N_TOK * 4);
  float* wtsb   = (float*)alloc((size_t)NEXP * N_TOK * 4);
  int*   counts = (int*)alloc(NEXP * CSTR * 4);
  int*   bases  = (int*)alloc(256);
  int*   meta   = (int*)alloc(256);
  int2*  idx    = (int2*)alloc((size_t)N_TOK * 8);

  const size_t hbufA = (size_t)HROWS * HID * 2;
  const size_t wtA   = (size_t)NEXP * DIM * HID * 2;
  __hip_bfloat16* hbuf = (__hip_bfloat16*)alloc(hbufA);
  __hip_bfloat16* w1t  = (__hip_bfloat16*)alloc(wtA);
  __hip_bfloat16* w2t  = (__hip_bfloat16*)alloc(wtA);
  const size_t used = (size_t)(w - (char*)d_ws);
  const size_t ybuf1 = (size_t)HROWS * DIM * 2;

  int SK;
  __hip_bfloat16* ybuf;
  if (ws_size >= used + 2 * ybuf1 + 4096) {
    SK = 2; ybuf = (__hip_bfloat16*)alloc(2 * ybuf1);
  } else {
    SK = 1; ybuf = w1t;  // w1t dead after gemm1
  }
  const int g2grid = (SK == 2) ? 8 * RTMAX : 4 * RTMAX;

  hipMemsetAsync(counts, 0, NEXP * CSTR * 4, stream);
  setup_kernel<<<8192 + N_TOK / 4, 256, 0, stream>>>(
      x, gamma, beta, conf_w, conf_b, rw, rb, w1, w1t,
      xn, out, counts, lists, wtsb, idx);
  bases_kernel<<<1, 64, 0, stream>>>(counts, bases, meta);
  gemm1_kernel<<<NG1 + 8192, 256, 0, stream>>>(xn, w1t, b1, lists, counts, bases, meta,
                                               hbuf, w2, w2t);
  gemm2_kernel<<<g2grid, 256, 0, stream>>>(hbuf, w2t, counts, bases, meta, ybuf, SK);
  combine_kernel<<<N_TOK / 4, 256, 0, stream>>>(x, ybuf, b2, idx, wtsb, bases, out, SK);
}

// Round 14
// 459.440 us; speedup vs baseline: 1.1747x; 1.1747x over previous
//
#include <hip/hip_runtime.h>
#include <hip/hip_bf16.h>

#define N_TOK 8192
#define DIM   1024
#define HID   4096
#define NEXP  8
#define CSTR  64    // counts stride in ints
#define RTMAX 136   // worst-case total 128-row tiles (16384/128 + 8 partials)
#define HROWS 16896 // hbuf/ybuf row capacity
#define EPS   264   // epilogue LDS stride (shorts)
#define NG1   (8 * 2 * RTMAX)  // gemm1 gemm-blocks; w2-transpose blocks appended

using bf16x8 = __attribute__((ext_vector_type(8))) short;
using f32x4  = __attribute__((ext_vector_type(4))) float;

__device__ __forceinline__ void gload_lds16(const void* g, void* l) {
  __builtin_amdgcn_global_load_lds(
      (const __attribute__((address_space(1))) unsigned int*)g,
      (__attribute__((address_space(3))) unsigned int*)l, 16, 0, 0);
}

__device__ __forceinline__ float wredsum(float v) {
#pragma unroll
  for (int off = 32; off > 0; off >>= 1) v += __shfl_xor(v, off, 64);
  return v;
}

__device__ __forceinline__ unsigned short f2bf(float f) {
  __hip_bfloat16 h = __float2bfloat16(f);
  return *reinterpret_cast<unsigned short*>(&h);
}
__device__ __forceinline__ float bf2f(unsigned short u) {
  return __uint_as_float((unsigned)u << 16);
}

// ---------------- transpose body: fp32 [R][C] tile -> bf16 [C][R] ----------------
__device__ __forceinline__ void transpose_body(
    const float* __restrict__ src, __hip_bfloat16* __restrict__ dst,
    int R, int C, int c0, int r0, float (*tile)[65]) {
  const int tid = threadIdx.x;
  const int tx = tid & 15, ty = tid >> 4;
#pragma unroll
  for (int k = 0; k < 4; k++) {
    const int row = ty + k * 16;
    const float4 v = *(const float4*)(src + (size_t)(r0 + row) * C + c0 + tx * 4);
    tile[row][tx * 4 + 0] = v.x; tile[row][tx * 4 + 1] = v.y;
    tile[row][tx * 4 + 2] = v.z; tile[row][tx * 4 + 3] = v.w;
  }
  __syncthreads();
#pragma unroll
  for (int k = 0; k < 4; k++) {
    const int orow = ty + k * 16;
    ushort4 st;
    st.x = f2bf(tile[tx * 4 + 0][orow]);
    st.y = f2bf(tile[tx * 4 + 1][orow]);
    st.z = f2bf(tile[tx * 4 + 2][orow]);
    st.w = f2bf(tile[tx * 4 + 3][orow]);
    *(ushort4*)((unsigned short*)dst + (size_t)(c0 + orow) * R + r0 + tx * 4) = st;
  }
}

// ---------------- setup: fused {w1 transpose | prep}  (w2 transpose rides gemm1) ----------------
__global__ __launch_bounds__(256) void setup_kernel(
    const float* __restrict__ x, const float* __restrict__ gamma, const float* __restrict__ beta,
    const float* __restrict__ conf_w, const float* __restrict__ conf_b,
    const float* __restrict__ rw, const float* __restrict__ rb,
    const float* __restrict__ w1,
    __hip_bfloat16* __restrict__ w1t,
    __hip_bfloat16* __restrict__ xn, float* __restrict__ out,
    int* __restrict__ counts, int* __restrict__ lists, float* __restrict__ wts,
    int2* __restrict__ idx) {
  __shared__ float tile[64][65];
  const int b = (int)blockIdx.x;
  if (b < 8192) {
    const int z = b >> 10, r = b & 1023;
    const int cx = r & 63, ry = r >> 6;
    transpose_body(w1 + (size_t)z * DIM * HID, w1t + (size_t)z * DIM * HID,
                   DIM, HID, cx * 64, ry * 64, tile);
    return;
  }
  // ---- prep ----
  const int t = (b - 8192) * 4 + ((int)threadIdx.x >> 6);
  const int lane = threadIdx.x & 63;
  const float* xr = x + (size_t)t * DIM;

  float4 xv[4];
#pragma unroll
  for (int q = 0; q < 4; q++) xv[q] = *(const float4*)(xr + q * 256 + lane * 4);

  float s = 0.f, s2 = 0.f;
#pragma unroll
  for (int q = 0; q < 4; q++) {
    s  += xv[q].x + xv[q].y + xv[q].z + xv[q].w;
    s2 += xv[q].x * xv[q].x + xv[q].y * xv[q].y + xv[q].z * xv[q].z + xv[q].w * xv[q].w;
  }
  s = wredsum(s); s2 = wredsum(s2);
  const float mu  = s * (1.f / DIM);
  const float inv = rsqrtf(s2 * (1.f / DIM) - mu * mu + 1e-5f);

  float p[9];
#pragma unroll
  for (int e = 0; e < 9; e++) p[e] = 0.f;

#pragma unroll
  for (int q = 0; q < 4; q++) {
    const int d0 = q * 256 + lane * 4;
    const float4 g4 = *(const float4*)(gamma + d0);
    const float4 b4 = *(const float4*)(beta + d0);
    float v0 = (xv[q].x - mu) * inv * g4.x + b4.x;
    float v1 = (xv[q].y - mu) * inv * g4.y + b4.y;
    float v2 = (xv[q].z - mu) * inv * g4.z + b4.z;
    float v3 = (xv[q].w - mu) * inv * g4.w + b4.w;

    ushort4 st; st.x = f2bf(v0); st.y = f2bf(v1); st.z = f2bf(v2); st.w = f2bf(v3);
    *(ushort4*)((unsigned short*)xn + (size_t)t * DIM + d0) = st;
    *(float4*)(out + (size_t)N_TOK * DIM + N_TOK + (size_t)t * DIM + d0) = xv[q];

    const float vv[4] = {v0, v1, v2, v3};
#pragma unroll
    for (int j = 0; j < 4; j++) {
      const int d = d0 + j;
      const float v = vv[j];
      p[8] += v * conf_w[d];
      const float4 r0 = *(const float4*)(rw + d * 8);
      const float4 r1 = *(const float4*)(rw + d * 8 + 4);
      p[0] += v * r0.x; p[1] += v * r0.y; p[2] += v * r0.z; p[3] += v * r0.w;
      p[4] += v * r1.x; p[5] += v * r1.y; p[6] += v * r1.z; p[7] += v * r1.w;
    }
  }
#pragma unroll
  for (int e = 0; e < 9; e++) p[e] = wredsum(p[e]);

  if (lane == 0) {
    float L[8];
#pragma unroll
    for (int e = 0; e < 8; e++) L[e] = p[e] + rb[e];
    const float cl = p[8] + conf_b[0];
    out[(size_t)N_TOK * DIM + t] = 1.f / (1.f + expf(-cl));

    float mx = L[0];
#pragma unroll
    for (int e = 1; e < 8; e++) mx = fmaxf(mx, L[e]);
    float pe[8];
#pragma unroll
    for (int e = 0; e < 8; e++) pe[e] = expf(L[e] - mx);
    int i0 = 0; float v0 = pe[0];
#pragma unroll
    for (int e = 1; e < 8; e++) if (pe[e] > v0) { v0 = pe[e]; i0 = e; }
    int i1 = -1; float v1 = -1.f;
#pragma unroll
    for (int e = 0; e < 8; e++) if (e != i0 && pe[e] > v1) { v1 = pe[e]; i1 = e; }
    const float wsum = v0 + v1;
    const float w0 = v0 / wsum, w1v = v1 / wsum;
    int p0 = atomicAdd(&counts[i0 * CSTR], 1);
    lists[i0 * N_TOK + p0] = t; wts[i0 * N_TOK + p0] = w0;
    int p1 = atomicAdd(&counts[i1 * CSTR], 1);
    lists[i1 * N_TOK + p1] = t; wts[i1 * N_TOK + p1] = w1v;
    idx[t] = make_int2((i0 << 13) | p0, (i1 << 13) | p1);
  }
}

// ---------------- prefix sums: bases (rows) and meta (128-row tiles) ----------------
__global__ void bases_kernel(const int* __restrict__ counts, int* __restrict__ bases,
                             int* __restrict__ meta) {
  if (threadIdx.x == 0) {
    int s = 0, r = 0;
#pragma unroll
    for (int e = 0; e < NEXP; e++) {
      bases[e] = s; meta[e] = r;
      const int c = counts[e * CSTR];
      s += c; r += (c + 127) >> 7;
    }
    meta[NEXP] = r;
  }
}

// ======== 128x256 / BK=32 / 4-wave (per-wave 128x64 out) depth-2 pipeline ========
// (r11's proven core, verbatim.) Slot s (24 KB) at s*24576: A [128 rows][32] bf16
// at +0, B [256 rows][32] at +8192. Row = 64 B = 4 x 16B chunks; elem (r,k) at
// r*64 + ((k>>3) ^ ((r>>1)&3))*16 + (k&7)*2. gload_lds dest linear; swizzle
// pre-applied to SOURCE address and identically on ds_read (rule 21).
// Per tile t: vmcnt(6); s_barrier; stage(t+2); reads {a0,b0..b3,a1..a7};
// group m gated by lgkmcnt(7-m).

#define LGKM_SB(N)                                                            \
  asm volatile("s_waitcnt lgkmcnt(" #N ")" ::: "memory");                     \
  __builtin_amdgcn_sched_barrier(0);

#define MFMA_G(MI)                                                            \
  __builtin_amdgcn_s_setprio(1);                                              \
  _Pragma("unroll")                                                           \
  for (int n = 0; n < 4; n++)                                                 \
    acc[MI][n] = __builtin_amdgcn_mfma_f32_16x16x32_bf16(afr[MI], bfr[n], acc[MI][n], 0, 0, 0); \
  __builtin_amdgcn_s_setprio(0);

#define GEMM_CORE(NT)                                                                   \
  f32x4 acc[8][4] = {};                                                                 \
  stage(0, 0); stage(1, 24576);                                                         \
  for (int t = 0; t < (NT); ++t) {                                                      \
    const int pb = (t % 3) * 24576;                                                     \
    if (t + 1 < (NT)) { asm volatile("s_waitcnt vmcnt(6)" ::: "memory"); }              \
    else              { asm volatile("s_waitcnt vmcnt(0)" ::: "memory"); }              \
    __builtin_amdgcn_s_barrier();                                                       \
    if (t + 2 < (NT)) stage(t + 2, ((t + 2) % 3) * 24576);                              \
    const char* Ab = smem + pb + Abase;                                                 \
    const char* Bb = smem + pb + Bbase;                                                 \
    bf16x8 bfr[4], afr[8];                                                              \
    afr[0] = *(const bf16x8*)(Ab);                                                      \
    bfr[0] = *(const bf16x8*)(Bb);                                                      \
    bfr[1] = *(const bf16x8*)(Bb + 1024);                                               \
    __builtin_amdgcn_sched_barrier(0);                                                  \
    bfr[2] = *(const bf16x8*)(Bb + 2048);                                               \
    bfr[3] = *(const bf16x8*)(Bb + 3072);                                               \
    __builtin_amdgcn_sched_barrier(0);                                                  \
    _Pragma("unroll")                                                                   \
    for (int m = 1; m < 8; m++) {                                                       \
      afr[m] = *(const bf16x8*)(Ab + m * 1024);                                         \
      __builtin_amdgcn_sched_barrier(0);                                                \
    }                                                                                   \
    LGKM_SB(7) MFMA_G(0)                                                                \
    LGKM_SB(6) MFMA_G(1)                                                                \
    LGKM_SB(5) MFMA_G(2)                                                                \
    LGKM_SB(4) MFMA_G(3)                                                                \
    LGKM_SB(3) MFMA_G(4)                                                                \
    LGKM_SB(2) MFMA_G(5)                                                                \
    LGKM_SB(1) MFMA_G(6)                                                                \
    LGKM_SB(0) MFMA_G(7)                                                                \
  }

#define DECODE_TAIL()                                                         \
  if (rtg >= meta[NEXP]) return;                                              \
  int e = 0;                                                                  \
  _Pragma("unroll")                                                           \
  for (int k = 1; k < NEXP; k++) if (meta[k] <= rtg) e = k;                   \
  const int rt = rtg - meta[e];                                               \
  const int cnt = counts[e * CSTR];                                           \
  const int hbase = bases[e];

#define GEMM_COMMON()                                                         \
  const int tid = threadIdx.x;  /* 256 threads = 4 waves */                   \
  const int l = tid & 63;                                                     \
  const int wc = tid >> 6;                                                    \
  const int lr = l & 15;                                                      \
  const int pchunk = (l >> 4) ^ ((lr >> 1) & 3);                              \
  const int Abase = lr * 64 + pchunk * 16;                                    \
  const int Bbase = 8192 + (wc * 64 + lr) * 64 + pchunk * 16;                 \
  const int srow = tid >> 2;  /* staging row in [0,64) */                     \
  const int lc = (tid & 3) ^ ((srow >> 1) & 3);  /* source logical chunk */

// epilogue: acc -> LDS bf16 [128][EPS] -> 16B/lane coalesced stores (256 thr)
#define EPILOGUE(DSTROW)                                                      \
  __builtin_amdgcn_s_barrier();                                               \
  {                                                                           \
    unsigned short* ep = (unsigned short*)smem;                               \
    _Pragma("unroll")                                                         \
    for (int n = 0; n < 4; n++) {                                             \
      const int col = wc * 64 + n * 16 + lr;                                  \
      _Pragma("unroll")                                                       \
      for (int m = 0; m < 8; m++) {                                           \
        f32x4 v = acc[m][n];                                                  \
        _Pragma("unroll")                                                     \
        for (int j = 0; j < 4; j++) {                                         \
          const int row = m * 16 + (l >> 4) * 4 + j;                          \
          ep[row * EPS + col] = f2bf(v[j]);                                   \
        }                                                                     \
      }                                                                       \
    }                                                                         \
    asm volatile("s_waitcnt lgkmcnt(0)" ::: "memory");                        \
    __builtin_amdgcn_s_barrier();                                             \
    const int g = tid >> 5, u = tid & 31;                                     \
    _Pragma("unroll")                                                         \
    for (int i = 0; i < 16; i++) {                                            \
      const int row = i * 8 + g;                                              \
      const int pos = rt * 128 + row;                                         \
      if (pos < cnt) {                                                        \
        bf16x8 vv = *(const bf16x8*)(ep + row * EPS + u * 8);                 \
        *(bf16x8*)(DSTROW + u * 8) = vv;                                      \
      }                                                                       \
    }                                                                         \
  }

// ---------------- GEMM1 (+ co-scheduled w2 transpose blocks) ----------------
__global__ __launch_bounds__(256, 2) void gemm1_kernel(
    const __hip_bfloat16* __restrict__ xn, const __hip_bfloat16* __restrict__ w1t_b,
    const float* __restrict__ b1, const int* __restrict__ lists,
    const int* __restrict__ counts, const int* __restrict__ bases,
    const int* __restrict__ meta, __hip_bfloat16* __restrict__ hbuf,
    const float* __restrict__ w2, __hip_bfloat16* __restrict__ w2t) {
  __shared__ char smem[73728];
  if ((int)blockIdx.x >= NG1) {
    // w2 transpose: [HID,DIM] fp32 -> [DIM,HID] bf16, 64x64 tiles (runs under gemm1)
    const int bb = (int)blockIdx.x - NG1;
    const int z = bb >> 10, r = bb & 1023;
    const int cx = r & 15, ry = r >> 4;
    transpose_body(w2 + (size_t)z * HID * DIM, w2t + (size_t)z * HID * DIM,
                   HID, DIM, cx * 64, ry * 64, (float(*)[65])smem);
    return;
  }
  const int x_ = (int)blockIdx.x & 7;
  const int q_ = (int)blockIdx.x >> 3;
  const int rtg = q_ >> 1;
  const int panel = x_ * 2 + (q_ & 1);
  DECODE_TAIL()
  const int ct = panel;
  const int* list = lists + e * N_TOK;
  const __hip_bfloat16* w1t = w1t_b + (size_t)e * DIM * HID;
  GEMM_COMMON()

  const int ap0 = rt * 128 + srow, ap1 = ap0 + 64;
  const int tok0 = list[ap0 < cnt ? ap0 : 0];
  const int tok1 = list[ap1 < cnt ? ap1 : 0];
  const unsigned short* srcA0 = (const unsigned short*)xn + (size_t)tok0 * DIM + lc * 8;
  const unsigned short* srcA1 = (const unsigned short*)xn + (size_t)tok1 * DIM + lc * 8;
  const unsigned short* srcB0 = (const unsigned short*)w1t + (size_t)(ct * 256 + srow) * DIM + lc * 8;
  const unsigned short* srcB1 = (const unsigned short*)w1t + (size_t)(ct * 256 + 64 + srow) * DIM + lc * 8;
  const unsigned short* srcB2 = (const unsigned short*)w1t + (size_t)(ct * 256 + 128 + srow) * DIM + lc * 8;
  const unsigned short* srcB3 = (const unsigned short*)w1t + (size_t)(ct * 256 + 192 + srow) * DIM + lc * 8;

  auto stage = [&](int tt, int lbase) {
    gload_lds16(srcA0 + tt * 32, smem + lbase + tid * 16);
    gload_lds16(srcA1 + tt * 32, smem + lbase + 4096 + tid * 16);
    gload_lds16(srcB0 + tt * 32, smem + lbase + 8192 + tid * 16);
    gload_lds16(srcB1 + tt * 32, smem + lbase + 12288 + tid * 16);
    gload_lds16(srcB2 + tt * 32, smem + lbase + 16384 + tid * 16);
    gload_lds16(srcB3 + tt * 32, smem + lbase + 20480 + tid * 16);
  };

  GEMM_CORE(DIM / 32)

  const float bv[4] = {
    b1[e * HID + ct * 256 + wc * 64 + 0 * 16 + lr],
    b1[e * HID + ct * 256 + wc * 64 + 1 * 16 + lr],
    b1[e * HID + ct * 256 + wc * 64 + 2 * 16 + lr],
    b1[e * HID + ct * 256 + wc * 64 + 3 * 16 + lr]};
#pragma unroll
  for (int n = 0; n < 4; n++)
#pragma unroll
    for (int m = 0; m < 8; m++)
#pragma unroll
      for (int j = 0; j < 4; j++) acc[m][n][j] = fmaxf(acc[m][n][j] + bv[n], 0.f);
  EPILOGUE((unsigned short*)hbuf + (size_t)(hbase + pos) * HID + ct * 256)
}

// ---------------- GEMM2 (split-K x SK): ybuf[ksp][base+pos] = hbuf @ w2t^T ----------------
// SK==2 decode: ksp = xcd&1; the 4 ct-panels of one (rt,ksp) co-resident per XCD.
__global__ __launch_bounds__(256, 2) void gemm2_kernel(
    const __hip_bfloat16* __restrict__ hbuf, const __hip_bfloat16* __restrict__ w2t_b,
    const int* __restrict__ counts, const int* __restrict__ bases,
    const int* __restrict__ meta, __hip_bfloat16* __restrict__ ybuf, const int SK) {
  __shared__ char smem[73728];
  int panel, rtg;
  if (SK == 2) {
    const int x_ = (int)blockIdx.x & 7;
    const int q_ = (int)blockIdx.x >> 3;
    rtg = (q_ >> 2) * 4 + (x_ >> 1);
    panel = (x_ & 1) * 4 + (q_ & 3);
  } else {
    panel = (int)blockIdx.x / RTMAX;
    rtg = (int)blockIdx.x - panel * RTMAX;
  }
  DECODE_TAIL()
  const int ct = panel & 3;
  const int ksp = panel >> 2;
  const int kbase = ksp * (HID / SK);
  const __hip_bfloat16* w2t = w2t_b + (size_t)e * DIM * HID;
  GEMM_COMMON()

  const unsigned short* srcA0 = (const unsigned short*)hbuf +
      (size_t)(hbase + rt * 128 + srow) * HID + kbase + lc * 8;
  const unsigned short* srcA1 = (const unsigned short*)hbuf +
      (size_t)(hbase + rt * 128 + 64 + srow) * HID + kbase + lc * 8;
  const unsigned short* srcB0 = (const unsigned short*)w2t +
      (size_t)(ct * 256 + srow) * HID + kbase + lc * 8;
  const unsigned short* srcB1 = (const unsigned short*)w2t +
      (size_t)(ct * 256 + 64 + srow) * HID + kbase + lc * 8;
  const unsigned short* srcB2 = (const unsigned short*)w2t +
      (size_t)(ct * 256 + 128 + srow) * HID + kbase + lc * 8;
  const unsigned short* srcB3 = (const unsigned short*)w2t +
      (size_t)(ct * 256 + 192 + srow) * HID + kbase + lc * 8;

  auto stage = [&](int tt, int lbase) {
    gload_lds16(srcA0 + tt * 32, smem + lbase + tid * 16);
    gload_lds16(srcA1 + tt * 32, smem + lbase + 4096 + tid * 16);
    gload_lds16(srcB0 + tt * 32, smem + lbase + 8192 + tid * 16);
    gload_lds16(srcB1 + tt * 32, smem + lbase + 12288 + tid * 16);
    gload_lds16(srcB2 + tt * 32, smem + lbase + 16384 + tid * 16);
    gload_lds16(srcB3 + tt * 32, smem + lbase + 20480 + tid * 16);
  };

  const int nk = (HID / 32) / SK;
  GEMM_CORE(nk)

  EPILOGUE((unsigned short*)ybuf + ((size_t)ksp * HROWS + hbase + pos) * DIM + ct * 256)
}

// ---------------- combine: out[t] = x[t] + sum_a w_a * (sum_s y[s][a] + b2[e_a]) ----------------
__global__ __launch_bounds__(256) void combine_kernel(
    const float* __restrict__ x, const __hip_bfloat16* __restrict__ ybuf,
    const float* __restrict__ b2, const int2* __restrict__ idx,
    const float* __restrict__ wv, const int* __restrict__ bases,
    float* __restrict__ out, const int SK) {
  const int t = blockIdx.x * 4 + (threadIdx.x >> 6);
  const int lane = threadIdx.x & 63;
  const int2 iv = idx[t];
  const int e0 = iv.x >> 13, p0 = iv.x & (N_TOK - 1);
  const int e1 = iv.y >> 13, p1 = iv.y & (N_TOK - 1);
  const float w0 = wv[iv.x], w1 = wv[iv.y];
  const int r0 = bases[e0] + p0;
  const int r1 = bases[e1] + p1;
#pragma unroll
  for (int q = 0; q < 4; q++) {
    const int d0 = q * 256 + lane * 4;
    float4 o = *(const float4*)(x + (size_t)t * DIM + d0);
    float y0x = 0.f, y0y = 0.f, y0z = 0.f, y0w = 0.f;
    float y1x = 0.f, y1y = 0.f, y1z = 0.f, y1w = 0.f;
    for (int s = 0; s < SK; s++) {
      const ushort4 a = *(const ushort4*)((const unsigned short*)ybuf +
                          ((size_t)s * HROWS + r0) * DIM + d0);
      const ushort4 b = *(const ushort4*)((const unsigned short*)ybuf +
                          ((size_t)s * HROWS + r1) * DIM + d0);
      y0x += bf2f(a.x); y0y += bf2f(a.y); y0z += bf2f(a.z); y0w += bf2f(a.w);
      y1x += bf2f(b.x); y1y += bf2f(b.y); y1z += bf2f(b.z); y1w += bf2f(b.w);
    }
    const float4 bb0 = *(const float4*)(b2 + e0 * DIM + d0);
    const float4 bb1 = *(const float4*)(b2 + e1 * DIM + d0);
    o.x += w0 * (y0x + bb0.x) + w1 * (y1x + bb1.x);
    o.y += w0 * (y0y + bb0.y) + w1 * (y1y + bb1.y);
    o.z += w0 * (y0z + bb0.z) + w1 * (y1z + bb1.z);
    o.w += w0 * (y0w + bb0.w) + w1 * (y1w + bb1.w);
    *(float4*)(out + (size_t)t * DIM + d0) = o;
  }
}

extern "C" void kernel_launch(void* const* d_in, const int* in_sizes, int n_in,
                              void* d_out, int out_size, void* d_ws, size_t ws_size,
                              hipStream_t stream) {
  (void)in_sizes; (void)n_in; (void)out_size;
  const float* x      = (const float*)d_in[0];
  const float* gamma  = (const float*)d_in[1];
  const float* beta   = (const float*)d_in[2];
  const float* conf_w = (const float*)d_in[3];
  const float* conf_b = (const float*)d_in[4];
  const float* rw     = (const float*)d_in[5];
  const float* rb     = (const float*)d_in[6];
  const float* w1     = (const float*)d_in[7];
  const float* b1     = (const float*)d_in[8];
  const float* w2     = (const float*)d_in[9];
  const float* b2     = (const float*)d_in[10];
  float* out = (float*)d_out;

  char* w = (char*)d_ws;
  auto alloc = [&](size_t bytes) { char* p = w; w += (bytes + 255) & ~255ULL; return p; };

  __hip_bfloat16* xn = (__hip_bfloat16*)alloc((size_t)N_TOK * DIM * 2);
  int*   lists  = (int*)alloc((size_t)NEXP * N_TOK * 4);
  float* wtsb   = (float*)alloc((size_t)NEXP * N_TOK * 4);
  int*   counts = (int*)alloc(NEXP * CSTR * 4);
  int*   bases  = (int*)alloc(256);
  int*   meta   = (int*)alloc(256);
  int2*  idx    = (int2*)alloc((size_t)N_TOK * 8);

  const size_t hbufA = (size_t)HROWS * HID * 2;
  const size_t wtA   = (size_t)NEXP * DIM * HID * 2;
  __hip_bfloat16* hbuf = (__hip_bfloat16*)alloc(hbufA);
  __hip_bfloat16* w1t  = (__hip_bfloat16*)alloc(wtA);
  __hip_bfloat16* w2t  = (__hip_bfloat16*)alloc(wtA);
  const size_t used = (size_t)(w - (char*)d_ws);
  const size_t ybuf1 = (size_t)HROWS * DIM * 2;

  int SK;
  __hip_bfloat16* ybuf;
  if (ws_size >= used + 2 * ybuf1 + 4096) {
    SK = 2; ybuf = (__hip_bfloat16*)alloc(2 * ybuf1);
  } else {
    SK = 1; ybuf = w1t;  // w1t dead after gemm1
  }
  const int g2grid = (SK == 2) ? 8 * RTMAX : 4 * RTMAX;

  hipMemsetAsync(counts, 0, NEXP * CSTR * 4, stream);
  setup_kernel<<<8192 + N_TOK / 4, 256, 0, stream>>>(
      x, gamma, beta, conf_w, conf_b, rw, rb, w1, w1t,
      xn, out, counts, lists, wtsb, idx);
  bases_kernel<<<1, 64, 0, stream>>>(counts, bases, meta);
  gemm1_kernel<<<NG1 + 8192, 256, 0, stream>>>(xn, w1t, b1, lists, counts, bases, meta,
                                               hbuf, w2, w2t);
  gemm2_kernel<<<g2grid, 256, 0, stream>>>(hbuf, w2t, counts, bases, meta, ybuf, SK);
  combine_kernel<<<N_TOK / 4, 256, 0, stream>>>(x, ybuf, b2, idx, wtsb, bases, out, SK);
}